// Round 10
// baseline (148.479 us; speedup 1.0000x reference)
//
#include <hip/hip_runtime.h>

#define EPSF 1e-12f

typedef __attribute__((ext_vector_type(8))) short short8;
typedef __attribute__((ext_vector_type(4))) float f32x4;

__device__ __forceinline__ float rcpf(float x) { return __builtin_amdgcn_rcpf(x); }

// tanh(x) = 1 - 2/(1+e^{2x}); saturates correctly without clamping
__device__ __forceinline__ float tanh_fast(float x) {
    float e = __expf(2.f * x);
    return 1.f - 2.f * rcpf(e + 1.f);
}

union U8 { short8 s; unsigned int u[4]; };

__device__ __forceinline__ unsigned int hi2(float x, float y) {
    // (bf16_trunc(y) << 16) | bf16_trunc(x)
    return __builtin_amdgcn_perm(__float_as_uint(y), __float_as_uint(x), 0x07060302u);
}
__device__ __forceinline__ float resid(float x) {
    return x - __uint_as_float(__float_as_uint(x) & 0xFFFF0000u);
}
// elements in slot order: a[0..3] -> slots 0..3, b[0..3] -> slots 4..7
__device__ __forceinline__ void pack8v(f32x4 a, f32x4 b, short8& hs, short8& ls) {
    U8 H, L;
    H.u[0] = hi2(a[0], a[1]); H.u[1] = hi2(a[2], a[3]);
    H.u[2] = hi2(b[0], b[1]); H.u[3] = hi2(b[2], b[3]);
    L.u[0] = hi2(resid(a[0]), resid(a[1])); L.u[1] = hi2(resid(a[2]), resid(a[3]));
    L.u[2] = hi2(resid(b[0]), resid(b[1])); L.u[3] = hi2(resid(b[2]), resid(b[3]));
    hs = H.s; ls = L.s;
}

struct Geom {
    float st0, st1, st2, st3, st4;
    float ep0,ep1,ep2, en0,en1,en2;
    float lp, ln, ilp, iln, il0p, il0n, idenom;
    float tp0,tp1,tp2, tn0,tn1,tn2;
    float kb0,kb1,kb2;
    float m1p0,m1p1,m1p2, m2p0,m2p1,m2p2;
    float m1n0,m1n1,m1n2, m2n0,m2n1,m2n2;
    float m1s0,m1s1,m1s2, m2s0,m2s1,m2s2;
};

__device__ __forceinline__ Geom compute_geom(
        const float* __restrict__ q, const int* __restrict__ spr,
        const float* __restrict__ l0e, const float* __restrict__ d1i,
        const float* __restrict__ d2i, int nodal) {
    Geom G;
    int ni = spr[0], nj = spr[1], nk = spr[2], iep = spr[3], ien = spr[4];
    float xi0 = q[3*ni+0], xi1 = q[3*ni+1], xi2 = q[3*ni+2];
    float xj0 = q[3*nj+0], xj1 = q[3*nj+1], xj2 = q[3*nj+2];
    float xk0 = q[3*nk+0], xk1 = q[3*nk+1], xk2 = q[3*nk+2];
    float thp = q[nodal + iep], thn = q[nodal + ien];
    float l0p = l0e[iep], l0n = l0e[ien];
    float d1p0 = d1i[3*iep+0], d1p1 = d1i[3*iep+1], d1p2 = d1i[3*iep+2];
    float d2p0 = d2i[3*iep+0], d2p1 = d2i[3*iep+1], d2p2 = d2i[3*iep+2];
    float d1n0 = d1i[3*ien+0], d1n1 = d1i[3*ien+1], d1n2 = d1i[3*ien+2];
    float d2n0 = d2i[3*ien+0], d2n1 = d2i[3*ien+1], d2n2 = d2i[3*ien+2];

    G.ep0 = xj0-xi0; G.ep1 = xj1-xi1; G.ep2 = xj2-xi2;
    G.en0 = xk0-xj0; G.en1 = xk1-xj1; G.en2 = xk2-xj2;
    G.lp = sqrtf(G.ep0*G.ep0 + G.ep1*G.ep1 + G.ep2*G.ep2);
    G.ln = sqrtf(G.en0*G.en0 + G.en1*G.en1 + G.en2*G.en2);
    G.ilp = rcpf(G.lp + EPSF); G.iln = rcpf(G.ln + EPSF);
    G.tp0 = G.ep0*G.ilp; G.tp1 = G.ep1*G.ilp; G.tp2 = G.ep2*G.ilp;
    G.tn0 = G.en0*G.iln; G.tn1 = G.en1*G.iln; G.tn2 = G.en2*G.iln;
    float cdot = G.tp0*G.tn0 + G.tp1*G.tn1 + G.tp2*G.tn2;
    G.idenom = rcpf(1.f + cdot + EPSF);
    float cr0 = G.tp1*G.tn2 - G.tp2*G.tn1;
    float cr1 = G.tp2*G.tn0 - G.tp0*G.tn2;
    float cr2 = G.tp0*G.tn1 - G.tp1*G.tn0;
    G.kb0 = 2.f*cr0*G.idenom; G.kb1 = 2.f*cr1*G.idenom; G.kb2 = 2.f*cr2*G.idenom;
    float cp, sp; __sincosf(thp, &sp, &cp);
    float cn, sn; __sincosf(thn, &sn, &cn);
    G.m1p0 = cp*d1p0 + sp*d2p0; G.m1p1 = cp*d1p1 + sp*d2p1; G.m1p2 = cp*d1p2 + sp*d2p2;
    G.m2p0 = cp*d2p0 - sp*d1p0; G.m2p1 = cp*d2p1 - sp*d1p1; G.m2p2 = cp*d2p2 - sp*d1p2;
    G.m1n0 = cn*d1n0 + sn*d2n0; G.m1n1 = cn*d1n1 + sn*d2n1; G.m1n2 = cn*d1n2 + sn*d2n2;
    G.m2n0 = cn*d2n0 - sn*d1n0; G.m2n1 = cn*d2n1 - sn*d1n1; G.m2n2 = cn*d2n2 - sn*d1n2;
    G.m1s0 = G.m1p0+G.m1n0; G.m1s1 = G.m1p1+G.m1n1; G.m1s2 = G.m1p2+G.m1n2;
    G.m2s0 = G.m2p0+G.m2n0; G.m2s1 = G.m2p1+G.m2n1; G.m2s2 = G.m2p2+G.m2n2;
    G.il0p = rcpf(l0p); G.il0n = rcpf(l0n);
    G.st0 = G.lp*G.il0p - 1.f;
    G.st1 = G.ln*G.il0n - 1.f;
    G.st2 =  0.5f*(G.kb0*G.m2s0 + G.kb1*G.m2s1 + G.kb2*G.m2s2);
    G.st3 = -0.5f*(G.kb0*G.m1s0 + G.kb1*G.m1s1 + G.kb2*G.m1s2);
    G.st4 = thn - thp;
    return G;
}

// geometry backward from gs[5]; writes 11 force slots at stride `stride`
__device__ __forceinline__ void geom_backward_store(
        const Geom& G, const float gs0, const float gs1, const float gs2,
        const float gs3, const float gs4, float* fsb, size_t stride) {
    float gkb0 = 0.5f*(gs2*G.m2s0 - gs3*G.m1s0);
    float gkb1 = 0.5f*(gs2*G.m2s1 - gs3*G.m1s1);
    float gkb2 = 0.5f*(gs2*G.m2s2 - gs3*G.m1s2);

    float kbm1p = G.kb0*G.m1p0 + G.kb1*G.m1p1 + G.kb2*G.m1p2;
    float kbm2p = G.kb0*G.m2p0 + G.kb1*G.m2p1 + G.kb2*G.m2p2;
    float kbm1n = G.kb0*G.m1n0 + G.kb1*G.m1n1 + G.kb2*G.m1n2;
    float kbm2n = G.kb0*G.m2n0 + G.kb1*G.m2n1 + G.kb2*G.m2n2;
    float gthp = -gs4 - 0.5f*(gs2*kbm1p + gs3*kbm2p);
    float gthn =  gs4 - 0.5f*(gs2*kbm1n + gs3*kbm2n);

    float gcr0 = 2.f*gkb0*G.idenom, gcr1 = 2.f*gkb1*G.idenom, gcr2 = 2.f*gkb2*G.idenom;
    float gc = -(gkb0*G.kb0 + gkb1*G.kb1 + gkb2*G.kb2)*G.idenom;

    float gtp0 = G.tn1*gcr2 - G.tn2*gcr1 + gc*G.tn0;
    float gtp1 = G.tn2*gcr0 - G.tn0*gcr2 + gc*G.tn1;
    float gtp2 = G.tn0*gcr1 - G.tn1*gcr0 + gc*G.tn2;
    float gtn0 = gcr1*G.tp2 - gcr2*G.tp1 + gc*G.tp0;
    float gtn1 = gcr2*G.tp0 - gcr0*G.tp2 + gc*G.tp1;
    float gtn2 = gcr0*G.tp1 - gcr1*G.tp0 + gc*G.tp2;

    float gep0 = gtp0*G.ilp, gep1 = gtp1*G.ilp, gep2 = gtp2*G.ilp;
    float gilp = gtp0*G.ep0 + gtp1*G.ep1 + gtp2*G.ep2;
    float glp  = gs0*G.il0p - gilp*G.ilp*G.ilp;
    float tl   = glp*rcpf(G.lp);
    gep0 = fmaf(tl, G.ep0, gep0); gep1 = fmaf(tl, G.ep1, gep1); gep2 = fmaf(tl, G.ep2, gep2);

    float gen0 = gtn0*G.iln, gen1 = gtn1*G.iln, gen2 = gtn2*G.iln;
    float giln = gtn0*G.en0 + gtn1*G.en1 + gtn2*G.en2;
    float gln  = gs1*G.il0n - giln*G.iln*G.iln;
    float ul   = gln*rcpf(G.ln);
    gen0 = fmaf(ul, G.en0, gen0); gen1 = fmaf(ul, G.en1, gen1); gen2 = fmaf(ul, G.en2, gen2);

    fsb[0*stride] = gep0;        fsb[1*stride] = gep1;        fsb[2*stride] = gep2;
    fsb[3*stride] = gen0-gep0;   fsb[4*stride] = gen1-gep1;   fsb[5*stride] = gen2-gep2;
    fsb[6*stride] = -gen0;       fsb[7*stride] = -gen1;       fsb[8*stride] = -gen2;
    fsb[9*stride] = -gthp;       fsb[10*stride] = -gthn;
}

#define MFMA_BF16 __builtin_amdgcn_mfma_f32_16x16x32_bf16

// ---------------- prep: pre-format W2 fragments + params ----------------
__global__ void k_prep(const float* __restrict__ W2, const float* __restrict__ W1,
                       const float* __restrict__ b1, const float* __restrict__ b2,
                       const float* __restrict__ W3, const float* __restrict__ b3,
                       short* __restrict__ wfrag) {
    int t = threadIdx.x;
    for (int e = 0; e < 16; ++e) {
        int L = t + 256*e;             // L = i*64 + o
        float w = W2[L];
        unsigned int u = __float_as_uint(w);
        short hsv = (short)(u >> 16);
        float lo = w - __uint_as_float(u & 0xFFFF0000u);
        short lsv = (short)(__float_as_uint(lo) >> 16);
        int i = L >> 6, o = L & 63;
        int posf = ((o >> 4)*2 + (i >> 5))*512
                 + (((i >> 2) & 3)*16 + (o & 15))*8
                 + ((i >> 4) & 1)*4 + (i & 3);
        int posb = ((i >> 4)*2 + (o >> 5))*512
                 + (((o >> 2) & 3)*16 + (i & 15))*8
                 + ((o >> 4) & 1)*4 + (o & 3);
        wfrag[0*4096 + posf] = hsv;
        wfrag[1*4096 + posf] = lsv;
        wfrag[2*4096 + posb] = hsv;
        wfrag[3*4096 + posb] = lsv;
    }
    float* par = (float*)(wfrag + 16384);
    for (int u2 = t; u2 < 320; u2 += 256) par[u2] = W1[u2];
    if (t < 64) { par[320+t] = b1[t]; par[384+t] = b2[t]; par[448+t] = W3[t]; }
    if (t == 0) par[512] = b3[0];
}

// ---------------- fused force kernel: thread = spring, 4 MFMA rounds/wave ----------------
// Phase A: geometry fwd per lane, keep ONLY st[5].
// Phase B: 4 rounds of the verified MFMA-MLP body; round r uses st shfl'd from
//          lane r*16+m16; reduced gs routed back via g4==r (lane L owns spring base+L).
// Phase C: geometry recomputed per lane (memory-clobber fence blocks CSE carry),
//          backward + spring-major store at full lane utilization.
__global__ __launch_bounds__(256) void k_force_mfma(
    const float* __restrict__ x,
    const short* __restrict__ wfrag,
    const float* __restrict__ l0e,
    const float* __restrict__ d1i, const float* __restrict__ d2i,
    const int* __restrict__ springs,
    float* __restrict__ fs,             // [11][BS] spring-major
    int B, int S, int ndof, int nodal)
{
    __shared__ __align__(16) short sAll[17424];   // 32768 B frags + 2080 B params

    const int t = threadIdx.x;
    #pragma unroll
    for (int p = 0; p < 9; ++p) {
        int u = t*16 + p*4096;
        if (u < 34848)
            *(float4*)((char*)sAll + u) = *(const float4*)((const char*)wfrag + u);
    }
    __syncthreads();

    const float* sPar = (const float*)(sAll + 16384);
    const short8* Afh = (const short8*)&sAll[0];
    const short8* Afl = (const short8*)&sAll[4096];
    const short8* Abh = (const short8*)&sAll[8192];
    const short8* Abl = (const short8*)&sAll[12288];

    const int lane = t & 63;
    const int g4 = lane >> 4;          // lane-group 0..3
    const int m16 = lane & 15;         // MFMA row-col index
    const int BS = B * S;

    // ---- my spring (one per lane) ----
    int myspring = blockIdx.x * 256 + t;
    const bool myactive = myspring < BS;
    int spc = myactive ? myspring : 0;
    int mb = spc / S;
    int ms = spc - mb * S;
    const int* spr = springs + 5 * ms;
    const float* q = x + (size_t)mb * (size_t)(2 * ndof);

    // ---- Phase A: strains only (Geom dies here) ----
    float st0, st1, st2, st3, st4;
    {
        Geom G = compute_geom(q, spr, l0e, d1i, d2i, nodal);
        st0 = G.st0; st1 = G.st1; st2 = G.st2; st3 = G.st3; st4 = G.st4;
    }

    // per-lane row fragments (constant across rounds)
    f32x4 b2v[4], w3v[4];
    #pragma unroll
    for (int ot = 0; ot < 4; ++ot) {
        b2v[ot] = *(const f32x4*)&sPar[384 + ot*16 + g4*4];
        w3v[ot] = *(const f32x4*)&sPar[448 + ot*16 + g4*4];
    }
    const float b3v = sPar[512];

    float gk0 = 0.f, gk1 = 0.f, gk2 = 0.f, gk3 = 0.f, gk4 = 0.f;

    #pragma unroll 1
    for (int r = 0; r < 4; ++r) {
        // ---- broadcast st of round-r springs (held by lane 16r+m16) ----
        const int src = r*16 + m16;
        float s0 = __shfl(st0, src, 64);
        float s1 = __shfl(st1, src, 64);
        float s2 = __shfl(st2, src, 64);
        float s3 = __shfl(st3, src, 64);
        float s4 = __shfl(st4, src, 64);

        // ---- h1 at i = 16*it + 4*g4 + rr ----
        f32x4 h1v[4];
        #pragma unroll
        for (int it = 0; it < 4; ++it) {
            const int off = it*16 + g4*4;
            f32x4 b1f = *(const f32x4*)&sPar[320 + off];
            f32x4 wa = *(const f32x4*)&sPar[0*64 + off];
            f32x4 wb = *(const f32x4*)&sPar[1*64 + off];
            f32x4 wc = *(const f32x4*)&sPar[2*64 + off];
            f32x4 wd = *(const f32x4*)&sPar[3*64 + off];
            f32x4 we = *(const f32x4*)&sPar[4*64 + off];
            #pragma unroll
            for (int rr = 0; rr < 4; ++rr) {
                float z1 = b1f[rr] + s0*wa[rr] + s1*wb[rr] + s2*wc[rr]
                         + s3*wd[rr] + s4*we[rr];
                h1v[it][rr] = tanh_fast(z1);
            }
        }

        // ---- pack h1 into B fragments (slot order = lambda) ----
        short8 bh0, bl0, bh1, bl1;
        pack8v(h1v[0], h1v[1], bh0, bl0);   // kc=0: it 0,1
        pack8v(h1v[2], h1v[3], bh1, bl1);   // kc=1: it 2,3

        // ---- forward: z2^T[o][spring] ----
        f32x4 acc[4];
        #pragma unroll
        for (int ot = 0; ot < 4; ++ot) acc[ot] = b2v[ot];

        #pragma unroll
        for (int ot = 0; ot < 4; ++ot) {
            short8 ah0 = Afh[(ot*2+0)*64 + lane];
            short8 al0 = Afl[(ot*2+0)*64 + lane];
            short8 ah1 = Afh[(ot*2+1)*64 + lane];
            short8 al1 = Afl[(ot*2+1)*64 + lane];
            acc[ot] = MFMA_BF16(ah0, bh0, acc[ot], 0, 0, 0);
            acc[ot] = MFMA_BF16(ah0, bl0, acc[ot], 0, 0, 0);
            acc[ot] = MFMA_BF16(al0, bh0, acc[ot], 0, 0, 0);
            acc[ot] = MFMA_BF16(ah1, bh1, acc[ot], 0, 0, 0);
            acc[ot] = MFMA_BF16(ah1, bl1, acc[ot], 0, 0, 0);
            acc[ot] = MFMA_BF16(al1, bh1, acc[ot], 0, 0, 0);
        }

        // ---- middle: h2 = tanh(z2); z3 (+2 shfl); sig; gz2 in place ----
        float z3 = 0.f;
        #pragma unroll
        for (int ot = 0; ot < 4; ++ot)
            #pragma unroll
            for (int rr = 0; rr < 4; ++rr) {
                float h2 = tanh_fast(acc[ot][rr]);
                acc[ot][rr] = h2;
                z3 = fmaf(h2, w3v[ot][rr], z3);
            }
        z3 += __shfl_xor(z3, 16, 64);
        z3 += __shfl_xor(z3, 32, 64);
        z3 += b3v;
        float sig = rcpf(1.f + __expf(-z3));       // softplus'

        #pragma unroll
        for (int ot = 0; ot < 4; ++ot)
            #pragma unroll
            for (int rr = 0; rr < 4; ++rr) {
                float h2 = acc[ot][rr];
                acc[ot][rr] = sig * w3v[ot][rr] * (1.f - h2*h2);
            }

        // ---- backward: g[i][spring] = W2 @ gz2 ----
        pack8v(acc[0], acc[1], bh0, bl0);   // kc=0: o-tiles 0,1
        pack8v(acc[2], acc[3], bh1, bl1);   // kc=1: o-tiles 2,3

        f32x4 gg[4];
        #pragma unroll
        for (int it = 0; it < 4; ++it) gg[it] = (f32x4){0.f, 0.f, 0.f, 0.f};

        #pragma unroll
        for (int it = 0; it < 4; ++it) {
            short8 ah0 = Abh[(it*2+0)*64 + lane];
            short8 al0 = Abl[(it*2+0)*64 + lane];
            short8 ah1 = Abh[(it*2+1)*64 + lane];
            short8 al1 = Abl[(it*2+1)*64 + lane];
            gg[it] = MFMA_BF16(ah0, bh0, gg[it], 0, 0, 0);
            gg[it] = MFMA_BF16(ah0, bl0, gg[it], 0, 0, 0);
            gg[it] = MFMA_BF16(al0, bh0, gg[it], 0, 0, 0);
            gg[it] = MFMA_BF16(ah1, bh1, gg[it], 0, 0, 0);
            gg[it] = MFMA_BF16(ah1, bl1, gg[it], 0, 0, 0);
            gg[it] = MFMA_BF16(al1, bh1, gg[it], 0, 0, 0);
        }

        // ---- gz1 = g*(1-h1^2); gs partials; reduce over lane-groups ----
        float p0 = 0.f, p1 = 0.f, p2 = 0.f, p3 = 0.f, p4 = 0.f;
        #pragma unroll
        for (int it = 0; it < 4; ++it) {
            const int off = it*16 + g4*4;
            f32x4 wa = *(const f32x4*)&sPar[0*64 + off];
            f32x4 wb = *(const f32x4*)&sPar[1*64 + off];
            f32x4 wc = *(const f32x4*)&sPar[2*64 + off];
            f32x4 wd = *(const f32x4*)&sPar[3*64 + off];
            f32x4 we = *(const f32x4*)&sPar[4*64 + off];
            #pragma unroll
            for (int rr = 0; rr < 4; ++rr) {
                float hv = h1v[it][rr];
                float gz1 = gg[it][rr] * (1.f - hv*hv);
                p0 = fmaf(gz1, wa[rr], p0);
                p1 = fmaf(gz1, wb[rr], p1);
                p2 = fmaf(gz1, wc[rr], p2);
                p3 = fmaf(gz1, wd[rr], p3);
                p4 = fmaf(gz1, we[rr], p4);
            }
        }
        p0 += __shfl_xor(p0, 16, 64); p0 += __shfl_xor(p0, 32, 64);
        p1 += __shfl_xor(p1, 16, 64); p1 += __shfl_xor(p1, 32, 64);
        p2 += __shfl_xor(p2, 16, 64); p2 += __shfl_xor(p2, 32, 64);
        p3 += __shfl_xor(p3, 16, 64); p3 += __shfl_xor(p3, 32, 64);
        p4 += __shfl_xor(p4, 16, 64); p4 += __shfl_xor(p4, 32, 64);

        // ---- route this round's gs to the owning lanes (g4 == r) ----
        if (g4 == r) { gk0 = p0; gk1 = p1; gk2 = p2; gk3 = p3; gk4 = p4; }
    }

    // fence: force Phase C to re-load/recompute geometry rather than carry it
    asm volatile("" ::: "memory");

    // ---- Phase C: geometry recompute + backward + store (full lane util) ----
    if (myactive) {
        Geom G = compute_geom(q, spr, l0e, d1i, d2i, nodal);
        geom_backward_store(G, gk0, gk1, gk2, gk3, gk4, fs + myspring, (size_t)BS);
    }
}

// ---------------- fallback: scalar per-thread kernel with atomics ----------------
__global__ __launch_bounds__(256) void k_force_scalar(
    const float* __restrict__ x,
    const float* __restrict__ W1, const float* __restrict__ b1,
    const float* __restrict__ W2, const float* __restrict__ b2,
    const float* __restrict__ W3, const float* __restrict__ b3,
    const float* __restrict__ Mff,
    const float* __restrict__ l0e,
    const float* __restrict__ d1i, const float* __restrict__ d2i,
    const int* __restrict__ springs,
    float* __restrict__ out,
    int B, int S, int ndof, int nodal)
{
    int tid = blockIdx.x * 256 + threadIdx.x;
    if (tid >= B * S) return;
    int b = tid / S;
    int s = tid - b * S;
    const int* spr = springs + 5 * s;
    const float* q = x + (size_t)b * (size_t)(2 * ndof);
    Geom G = compute_geom(q, spr, l0e, d1i, d2i, nodal);
    float st0 = G.st0, st1 = G.st1, st2 = G.st2, st3 = G.st3, st4 = G.st4;

    const float4* W2v = reinterpret_cast<const float4*>(W2);
    float accv[64];
    #pragma unroll
    for (int j = 0; j < 64; ++j) accv[j] = b2[j];
    #pragma unroll 4
    for (int i = 0; i < 64; ++i) {
        float z1 = b1[i] + st0*W1[i] + st1*W1[64+i] + st2*W1[128+i]
                 + st3*W1[192+i] + st4*W1[256+i];
        float hi = tanh_fast(z1);
        #pragma unroll
        for (int j4 = 0; j4 < 16; ++j4) {
            float4 w = W2v[i*16 + j4];
            accv[4*j4+0] = fmaf(hi, w.x, accv[4*j4+0]);
            accv[4*j4+1] = fmaf(hi, w.y, accv[4*j4+1]);
            accv[4*j4+2] = fmaf(hi, w.z, accv[4*j4+2]);
            accv[4*j4+3] = fmaf(hi, w.w, accv[4*j4+3]);
        }
    }
    float z3 = b3[0];
    #pragma unroll
    for (int j = 0; j < 64; ++j) {
        float h2 = tanh_fast(accv[j]); accv[j] = h2;
        z3 = fmaf(h2, W3[j], z3);
    }
    float sig = rcpf(1.f + __expf(-z3));
    #pragma unroll
    for (int j = 0; j < 64; ++j) {
        float h2 = accv[j];
        accv[j] = sig * W3[j] * (1.f - h2*h2);
    }
    float gs0 = 0.f, gs1 = 0.f, gs2 = 0.f, gs3 = 0.f, gs4 = 0.f;
    #pragma unroll 4
    for (int i = 0; i < 64; ++i) {
        float g0 = 0.f;
        #pragma unroll
        for (int j4 = 0; j4 < 16; ++j4) {
            float4 w = W2v[i*16 + j4];
            g0 += w.x*accv[4*j4+0] + w.y*accv[4*j4+1] + w.z*accv[4*j4+2] + w.w*accv[4*j4+3];
        }
        float z1 = b1[i] + st0*W1[i] + st1*W1[64+i] + st2*W1[128+i]
                 + st3*W1[192+i] + st4*W1[256+i];
        float h1 = tanh_fast(z1);
        float gz1 = g0 * (1.f - h1*h1);
        gs0 = fmaf(W1[i],     gz1, gs0);
        gs1 = fmaf(W1[64+i],  gz1, gs1);
        gs2 = fmaf(W1[128+i], gz1, gs2);
        gs3 = fmaf(W1[192+i], gz1, gs3);
        gs4 = fmaf(W1[256+i], gz1, gs4);
    }
    float gkb0 = 0.5f*(gs2*G.m2s0 - gs3*G.m1s0);
    float gkb1 = 0.5f*(gs2*G.m2s1 - gs3*G.m1s1);
    float gkb2 = 0.5f*(gs2*G.m2s2 - gs3*G.m1s2);
    float kbm1p = G.kb0*G.m1p0 + G.kb1*G.m1p1 + G.kb2*G.m1p2;
    float kbm2p = G.kb0*G.m2p0 + G.kb1*G.m2p1 + G.kb2*G.m2p2;
    float kbm1n = G.kb0*G.m1n0 + G.kb1*G.m1n1 + G.kb2*G.m1n2;
    float kbm2n = G.kb0*G.m2n0 + G.kb1*G.m2n1 + G.kb2*G.m2n2;
    float gthp = -gs4 - 0.5f*(gs2*kbm1p + gs3*kbm2p);
    float gthn =  gs4 - 0.5f*(gs2*kbm1n + gs3*kbm2n);
    float gcr0 = 2.f*gkb0*G.idenom, gcr1 = 2.f*gkb1*G.idenom, gcr2 = 2.f*gkb2*G.idenom;
    float gc = -(gkb0*G.kb0 + gkb1*G.kb1 + gkb2*G.kb2)*G.idenom;
    float gtp0 = G.tn1*gcr2 - G.tn2*gcr1 + gc*G.tn0;
    float gtp1 = G.tn2*gcr0 - G.tn0*gcr2 + gc*G.tn1;
    float gtp2 = G.tn0*gcr1 - G.tn1*gcr0 + gc*G.tn2;
    float gtn0 = gcr1*G.tp2 - gcr2*G.tp1 + gc*G.tp0;
    float gtn1 = gcr2*G.tp0 - gcr0*G.tp2 + gc*G.tp1;
    float gtn2 = gcr0*G.tp1 - gcr1*G.tp0 + gc*G.tp2;
    float gep0 = gtp0*G.ilp, gep1 = gtp1*G.ilp, gep2 = gtp2*G.ilp;
    float gilp = gtp0*G.ep0 + gtp1*G.ep1 + gtp2*G.ep2;
    float glp  = gs0*G.il0p - gilp*G.ilp*G.ilp;
    float tl   = glp*rcpf(G.lp);
    gep0 = fmaf(tl, G.ep0, gep0); gep1 = fmaf(tl, G.ep1, gep1); gep2 = fmaf(tl, G.ep2, gep2);
    float gen0 = gtn0*G.iln, gen1 = gtn1*G.iln, gen2 = gtn2*G.iln;
    float giln = gtn0*G.en0 + gtn1*G.en1 + gtn2*G.en2;
    float gln  = gs1*G.il0n - giln*G.iln*G.iln;
    float ul   = gln*rcpf(G.ln);
    gen0 = fmaf(ul, G.en0, gen0); gen1 = fmaf(ul, G.en1, gen1); gen2 = fmaf(ul, G.en2, gen2);
    float* oa = out + (size_t)b * (size_t)(2*ndof) + ndof;
    const size_t nd1 = (size_t)ndof + 1;
    int ni = spr[0], nj = spr[1], nk = spr[2];
    int di = 3*ni, dj = 3*nj, dk = 3*nk, dp = nodal + spr[3], dn = nodal + spr[4];
    atomicAdd(oa + di + 0, ( gep0) * rcpf(Mff[(size_t)(di+0)*nd1]));
    atomicAdd(oa + di + 1, ( gep1) * rcpf(Mff[(size_t)(di+1)*nd1]));
    atomicAdd(oa + di + 2, ( gep2) * rcpf(Mff[(size_t)(di+2)*nd1]));
    atomicAdd(oa + dj + 0, (gen0-gep0) * rcpf(Mff[(size_t)(dj+0)*nd1]));
    atomicAdd(oa + dj + 1, (gen1-gep1) * rcpf(Mff[(size_t)(dj+1)*nd1]));
    atomicAdd(oa + dj + 2, (gen2-gep2) * rcpf(Mff[(size_t)(dj+2)*nd1]));
    atomicAdd(oa + dk + 0, (-gen0) * rcpf(Mff[(size_t)(dk+0)*nd1]));
    atomicAdd(oa + dk + 1, (-gen1) * rcpf(Mff[(size_t)(dk+1)*nd1]));
    atomicAdd(oa + dk + 2, (-gen2) * rcpf(Mff[(size_t)(dk+2)*nd1]));
    atomicAdd(oa + dp, (-gthp) * rcpf(Mff[(size_t)dp*nd1]));
    atomicAdd(oa + dn, (-gthn) * rcpf(Mff[(size_t)dn*nd1]));
}

// out[:, :ndof] = v ; out[:, ndof:] = (f_ext - Cdd*v + gather(fs)) / Mdd
// fs layout: [11][BS] spring-major (slot stride BS, spring index b*S+s)
template<int GATHER>
__global__ void k_out(const float* __restrict__ x, const float* __restrict__ C,
                      const float* __restrict__ Mff, const float* __restrict__ fext,
                      const float* __restrict__ fs, float* __restrict__ out,
                      int B, int ndof, int nodal, int S) {
    int idx = blockIdx.x * blockDim.x + threadIdx.x;
    if (idx >= B * ndof) return;
    int b = idx / ndof;
    int d = idx - b * ndof;
    size_t row = (size_t)b * (size_t)(2 * ndof);
    const size_t nd1 = (size_t)ndof + 1;
    float vd = x[row + ndof + d];
    out[row + d] = vd;
    float acc = fext[d] - C[(size_t)d * nd1] * vd;
    if (GATHER) {
        const size_t BS = (size_t)B * S;
        const size_t bb = (size_t)b * S;
        if (d < nodal) {
            int n = d / 3, c = d - 3 * n;
            if (n < S)            acc += fs[(size_t)(0 + c) * BS + bb + n];
            if (n >= 1 && n <= S) acc += fs[(size_t)(3 + c) * BS + bb + n - 1];
            if (n >= 2)           acc += fs[(size_t)(6 + c) * BS + bb + n - 2];
        } else {
            int e = d - nodal;
            if (e < S)  acc += fs[(size_t)9 * BS + bb + e];
            if (e >= 1) acc += fs[(size_t)10 * BS + bb + e - 1];
        }
    }
    out[row + ndof + d] = acc * rcpf(Mff[(size_t)d * nd1]);
}

extern "C" void kernel_launch(void* const* d_in, const int* in_sizes, int n_in,
                              void* d_out, int out_size, void* d_ws, size_t ws_size,
                              hipStream_t stream) {
    const float* x    = (const float*)d_in[1];
    const float* W1   = (const float*)d_in[2];
    const float* b1   = (const float*)d_in[3];
    const float* W2   = (const float*)d_in[4];
    const float* b2   = (const float*)d_in[5];
    const float* W3   = (const float*)d_in[6];
    const float* b3   = (const float*)d_in[7];
    const float* C    = (const float*)d_in[8];
    const float* Mff  = (const float*)d_in[9];
    const float* fext = (const float*)d_in[10];
    const float* l0e  = (const float*)d_in[11];
    const float* d1i  = (const float*)d_in[12];
    const float* d2i  = (const float*)d_in[13];
    const int* springs = (const int*)d_in[14];
    float* out = (float*)d_out;

    int ndof  = in_sizes[10];
    int E     = in_sizes[11];
    int S     = in_sizes[14] / 5;
    int nodal = ndof - E;
    int B     = in_sizes[1] / (2 * ndof);

    int BS   = B * S;
    int totO = B * ndof;
    const size_t fragBytes = 34848;   // 32768 frag + 2080 params (16-aligned)
    size_t ws_need = fragBytes + (size_t)BS * 11 * sizeof(float);

    if (d_ws && ws_size >= ws_need) {
        short* wfrag = (short*)d_ws;
        float* fs = (float*)((char*)d_ws + fragBytes);
        k_prep<<<1, 256, 0, stream>>>(W2, W1, b1, b2, W3, b3, wfrag);
        int nblk = (BS + 255) / 256;   // 256 springs per block (4 waves x 64)
        k_force_mfma<<<nblk, 256, 0, stream>>>(x, wfrag, l0e, d1i, d2i, springs, fs,
                                               B, S, ndof, nodal);
        k_out<1><<<(totO + 255) / 256, 256, 0, stream>>>(x, C, Mff, fext, fs, out,
                                                         B, ndof, nodal, S);
    } else {
        k_out<0><<<(totO + 255) / 256, 256, 0, stream>>>(x, C, Mff, fext, nullptr, out,
                                                         B, ndof, nodal, S);
        k_force_scalar<<<(BS + 255) / 256, 256, 0, stream>>>(x, W1, b1, W2, b2, W3, b3, Mff,
                                                             l0e, d1i, d2i, springs, out,
                                                             B, S, ndof, nodal);
    }
}

// Round 11
// 129.243 us; speedup vs baseline: 1.1488x; 1.1488x over previous
//
#include <hip/hip_runtime.h>

#define EPSF 1e-12f

typedef __attribute__((ext_vector_type(8))) short short8;
typedef __attribute__((ext_vector_type(4))) float f32x4;

__device__ __forceinline__ float rcpf(float x) { return __builtin_amdgcn_rcpf(x); }

// tanh(x) = 1 - 2/(1+e^{2x}); saturates correctly without clamping
__device__ __forceinline__ float tanh_fast(float x) {
    float e = __expf(2.f * x);
    return 1.f - 2.f * rcpf(e + 1.f);
}

union U8 { short8 s; unsigned int u[4]; };

__device__ __forceinline__ unsigned int hi2(float x, float y) {
    // (bf16_trunc(y) << 16) | bf16_trunc(x)
    return __builtin_amdgcn_perm(__float_as_uint(y), __float_as_uint(x), 0x07060302u);
}
__device__ __forceinline__ float resid(float x) {
    return x - __uint_as_float(__float_as_uint(x) & 0xFFFF0000u);
}
// elements in slot order: a[0..3] -> slots 0..3, b[0..3] -> slots 4..7
__device__ __forceinline__ void pack8v(f32x4 a, f32x4 b, short8& hs, short8& ls) {
    U8 H, L;
    H.u[0] = hi2(a[0], a[1]); H.u[1] = hi2(a[2], a[3]);
    H.u[2] = hi2(b[0], b[1]); H.u[3] = hi2(b[2], b[3]);
    L.u[0] = hi2(resid(a[0]), resid(a[1])); L.u[1] = hi2(resid(a[2]), resid(a[3]));
    L.u[2] = hi2(resid(b[0]), resid(b[1])); L.u[3] = hi2(resid(b[2]), resid(b[3]));
    hs = H.s; ls = L.s;
}

struct Geom {
    float st0, st1, st2, st3, st4;
    float ep0,ep1,ep2, en0,en1,en2;
    float lp, ln, ilp, iln, il0p, il0n, idenom;
    float tp0,tp1,tp2, tn0,tn1,tn2;
    float kb0,kb1,kb2;
    float m1p0,m1p1,m1p2, m2p0,m2p1,m2p2;
    float m1n0,m1n1,m1n2, m2n0,m2n1,m2n2;
    float m1s0,m1s1,m1s2, m2s0,m2s1,m2s2;
};

__device__ __forceinline__ Geom compute_geom(
        const float* __restrict__ q, const int* __restrict__ spr,
        const float* __restrict__ l0e, const float* __restrict__ d1i,
        const float* __restrict__ d2i, int nodal) {
    Geom G;
    int ni = spr[0], nj = spr[1], nk = spr[2], iep = spr[3], ien = spr[4];
    float xi0 = q[3*ni+0], xi1 = q[3*ni+1], xi2 = q[3*ni+2];
    float xj0 = q[3*nj+0], xj1 = q[3*nj+1], xj2 = q[3*nj+2];
    float xk0 = q[3*nk+0], xk1 = q[3*nk+1], xk2 = q[3*nk+2];
    float thp = q[nodal + iep], thn = q[nodal + ien];
    float l0p = l0e[iep], l0n = l0e[ien];
    float d1p0 = d1i[3*iep+0], d1p1 = d1i[3*iep+1], d1p2 = d1i[3*iep+2];
    float d2p0 = d2i[3*iep+0], d2p1 = d2i[3*iep+1], d2p2 = d2i[3*iep+2];
    float d1n0 = d1i[3*ien+0], d1n1 = d1i[3*ien+1], d1n2 = d1i[3*ien+2];
    float d2n0 = d2i[3*ien+0], d2n1 = d2i[3*ien+1], d2n2 = d2i[3*ien+2];

    G.ep0 = xj0-xi0; G.ep1 = xj1-xi1; G.ep2 = xj2-xi2;
    G.en0 = xk0-xj0; G.en1 = xk1-xj1; G.en2 = xk2-xj2;
    G.lp = sqrtf(G.ep0*G.ep0 + G.ep1*G.ep1 + G.ep2*G.ep2);
    G.ln = sqrtf(G.en0*G.en0 + G.en1*G.en1 + G.en2*G.en2);
    G.ilp = rcpf(G.lp + EPSF); G.iln = rcpf(G.ln + EPSF);
    G.tp0 = G.ep0*G.ilp; G.tp1 = G.ep1*G.ilp; G.tp2 = G.ep2*G.ilp;
    G.tn0 = G.en0*G.iln; G.tn1 = G.en1*G.iln; G.tn2 = G.en2*G.iln;
    float cdot = G.tp0*G.tn0 + G.tp1*G.tn1 + G.tp2*G.tn2;
    G.idenom = rcpf(1.f + cdot + EPSF);
    float cr0 = G.tp1*G.tn2 - G.tp2*G.tn1;
    float cr1 = G.tp2*G.tn0 - G.tp0*G.tn2;
    float cr2 = G.tp0*G.tn1 - G.tp1*G.tn0;
    G.kb0 = 2.f*cr0*G.idenom; G.kb1 = 2.f*cr1*G.idenom; G.kb2 = 2.f*cr2*G.idenom;
    float cp, sp; __sincosf(thp, &sp, &cp);
    float cn, sn; __sincosf(thn, &sn, &cn);
    G.m1p0 = cp*d1p0 + sp*d2p0; G.m1p1 = cp*d1p1 + sp*d2p1; G.m1p2 = cp*d1p2 + sp*d2p2;
    G.m2p0 = cp*d2p0 - sp*d1p0; G.m2p1 = cp*d2p1 - sp*d1p1; G.m2p2 = cp*d2p2 - sp*d1p2;
    G.m1n0 = cn*d1n0 + sn*d2n0; G.m1n1 = cn*d1n1 + sn*d2n1; G.m1n2 = cn*d1n2 + sn*d2n2;
    G.m2n0 = cn*d2n0 - sn*d1n0; G.m2n1 = cn*d2n1 - sn*d1n1; G.m2n2 = cn*d2n2 - sn*d1n2;
    G.m1s0 = G.m1p0+G.m1n0; G.m1s1 = G.m1p1+G.m1n1; G.m1s2 = G.m1p2+G.m1n2;
    G.m2s0 = G.m2p0+G.m2n0; G.m2s1 = G.m2p1+G.m2n1; G.m2s2 = G.m2p2+G.m2n2;
    G.il0p = rcpf(l0p); G.il0n = rcpf(l0n);
    G.st0 = G.lp*G.il0p - 1.f;
    G.st1 = G.ln*G.il0n - 1.f;
    G.st2 =  0.5f*(G.kb0*G.m2s0 + G.kb1*G.m2s1 + G.kb2*G.m2s2);
    G.st3 = -0.5f*(G.kb0*G.m1s0 + G.kb1*G.m1s1 + G.kb2*G.m1s2);
    G.st4 = thn - thp;
    return G;
}

// geometry backward from gs[5]; writes 11 force slots at stride `stride`
__device__ __forceinline__ void geom_backward_store(
        const Geom& G, const float gs0, const float gs1, const float gs2,
        const float gs3, const float gs4, float* fsb, size_t stride) {
    float gkb0 = 0.5f*(gs2*G.m2s0 - gs3*G.m1s0);
    float gkb1 = 0.5f*(gs2*G.m2s1 - gs3*G.m1s1);
    float gkb2 = 0.5f*(gs2*G.m2s2 - gs3*G.m1s2);

    float kbm1p = G.kb0*G.m1p0 + G.kb1*G.m1p1 + G.kb2*G.m1p2;
    float kbm2p = G.kb0*G.m2p0 + G.kb1*G.m2p1 + G.kb2*G.m2p2;
    float kbm1n = G.kb0*G.m1n0 + G.kb1*G.m1n1 + G.kb2*G.m1n2;
    float kbm2n = G.kb0*G.m2n0 + G.kb1*G.m2n1 + G.kb2*G.m2n2;
    float gthp = -gs4 - 0.5f*(gs2*kbm1p + gs3*kbm2p);
    float gthn =  gs4 - 0.5f*(gs2*kbm1n + gs3*kbm2n);

    float gcr0 = 2.f*gkb0*G.idenom, gcr1 = 2.f*gkb1*G.idenom, gcr2 = 2.f*gkb2*G.idenom;
    float gc = -(gkb0*G.kb0 + gkb1*G.kb1 + gkb2*G.kb2)*G.idenom;

    float gtp0 = G.tn1*gcr2 - G.tn2*gcr1 + gc*G.tn0;
    float gtp1 = G.tn2*gcr0 - G.tn0*gcr2 + gc*G.tn1;
    float gtp2 = G.tn0*gcr1 - G.tn1*gcr0 + gc*G.tn2;
    float gtn0 = gcr1*G.tp2 - gcr2*G.tp1 + gc*G.tp0;
    float gtn1 = gcr2*G.tp0 - gcr0*G.tp2 + gc*G.tp1;
    float gtn2 = gcr0*G.tp1 - gcr1*G.tp0 + gc*G.tp2;

    float gep0 = gtp0*G.ilp, gep1 = gtp1*G.ilp, gep2 = gtp2*G.ilp;
    float gilp = gtp0*G.ep0 + gtp1*G.ep1 + gtp2*G.ep2;
    float glp  = gs0*G.il0p - gilp*G.ilp*G.ilp;
    float tl   = glp*rcpf(G.lp);
    gep0 = fmaf(tl, G.ep0, gep0); gep1 = fmaf(tl, G.ep1, gep1); gep2 = fmaf(tl, G.ep2, gep2);

    float gen0 = gtn0*G.iln, gen1 = gtn1*G.iln, gen2 = gtn2*G.iln;
    float giln = gtn0*G.en0 + gtn1*G.en1 + gtn2*G.en2;
    float gln  = gs1*G.il0n - giln*G.iln*G.iln;
    float ul   = gln*rcpf(G.ln);
    gen0 = fmaf(ul, G.en0, gen0); gen1 = fmaf(ul, G.en1, gen1); gen2 = fmaf(ul, G.en2, gen2);

    fsb[0*stride] = gep0;        fsb[1*stride] = gep1;        fsb[2*stride] = gep2;
    fsb[3*stride] = gen0-gep0;   fsb[4*stride] = gen1-gep1;   fsb[5*stride] = gen2-gep2;
    fsb[6*stride] = -gen0;       fsb[7*stride] = -gen1;       fsb[8*stride] = -gen2;
    fsb[9*stride] = -gthp;       fsb[10*stride] = -gthn;
}

#define MFMA_BF16 __builtin_amdgcn_mfma_f32_16x16x32_bf16

// ---------------- prep: pre-format W2 fragments + params ----------------
__global__ void k_prep(const float* __restrict__ W2, const float* __restrict__ W1,
                       const float* __restrict__ b1, const float* __restrict__ b2,
                       const float* __restrict__ W3, const float* __restrict__ b3,
                       short* __restrict__ wfrag) {
    int t = threadIdx.x;
    for (int e = 0; e < 16; ++e) {
        int L = t + 256*e;             // L = i*64 + o
        float w = W2[L];
        unsigned int u = __float_as_uint(w);
        short hsv = (short)(u >> 16);
        float lo = w - __uint_as_float(u & 0xFFFF0000u);
        short lsv = (short)(__float_as_uint(lo) >> 16);
        int i = L >> 6, o = L & 63;
        int posf = ((o >> 4)*2 + (i >> 5))*512
                 + (((i >> 2) & 3)*16 + (o & 15))*8
                 + ((i >> 4) & 1)*4 + (i & 3);
        int posb = ((i >> 4)*2 + (o >> 5))*512
                 + (((o >> 2) & 3)*16 + (i & 15))*8
                 + ((o >> 4) & 1)*4 + (o & 3);
        wfrag[0*4096 + posf] = hsv;
        wfrag[1*4096 + posf] = lsv;
        wfrag[2*4096 + posb] = hsv;
        wfrag[3*4096 + posb] = lsv;
    }
    float* par = (float*)(wfrag + 16384);
    for (int u2 = t; u2 < 320; u2 += 256) par[u2] = W1[u2];
    if (t < 64) { par[320+t] = b1[t]; par[384+t] = b2[t]; par[448+t] = W3[t]; }
    if (t == 0) par[512] = b3[0];
}

// ---------------- stage 1: strains (per-thread, full lane utilization) ----------------
__global__ __launch_bounds__(256) void k_strain(
    const float* __restrict__ x,
    const float* __restrict__ l0e,
    const float* __restrict__ d1i, const float* __restrict__ d2i,
    const int* __restrict__ springs,
    float* __restrict__ stbuf,          // [5][BS] spring-major
    int B, int S, int ndof, int nodal)
{
    int sp = blockIdx.x * 256 + threadIdx.x;
    int BS = B * S;
    if (sp >= BS) return;
    int b = sp / S;
    int s = sp - b * S;
    const int* spr = springs + 5 * s;
    const float* q = x + (size_t)b * (size_t)(2 * ndof);
    Geom G = compute_geom(q, spr, l0e, d1i, d2i, nodal);
    stbuf[0*(size_t)BS + sp] = G.st0;
    stbuf[1*(size_t)BS + sp] = G.st1;
    stbuf[2*(size_t)BS + sp] = G.st2;
    stbuf[3*(size_t)BS + sp] = G.st3;
    stbuf[4*(size_t)BS + sp] = G.st4;
}

// ---------------- stage 2: MFMA MLP, G-group chunked (stage LDS once) ----------------
// wave = 16 springs per group iteration; block processes CHUNK consecutive
// 64-spring groups with one LDS staging. st read / gs written in place.
#define CHUNK 8
__global__ __launch_bounds__(256) void k_mlp(
    const short* __restrict__ wfrag,
    float* buf,                         // st in / gs out, [5][BS]
    int BS, int ngroups)
{
    __shared__ __align__(16) short sAll[17424];   // 32768 B frags + 2080 B params

    const int t = threadIdx.x;
    #pragma unroll
    for (int p = 0; p < 9; ++p) {
        int u = t*16 + p*4096;
        if (u < 34848)
            *(float4*)((char*)sAll + u) = *(const float4*)((const char*)wfrag + u);
    }
    __syncthreads();

    const float* sPar = (const float*)(sAll + 16384);
    const short8* Afh = (const short8*)&sAll[0];
    const short8* Afl = (const short8*)&sAll[4096];
    const short8* Abh = (const short8*)&sAll[8192];
    const short8* Abl = (const short8*)&sAll[12288];

    const int lane = t & 63;
    const int wv = t >> 6;
    const int g4 = lane >> 4;          // lane-group 0..3
    const int m16 = lane & 15;         // spring within wave / MFMA row-col index

    // per-lane row fragments (constant across group iterations)
    f32x4 b2v[4], w3v[4];
    #pragma unroll
    for (int ot = 0; ot < 4; ++ot) {
        b2v[ot] = *(const f32x4*)&sPar[384 + ot*16 + g4*4];
        w3v[ot] = *(const f32x4*)&sPar[448 + ot*16 + g4*4];
    }
    const float b3v = sPar[512];

    #pragma unroll 1
    for (int j = 0; j < CHUNK; ++j) {
        int grp = blockIdx.x * CHUNK + j;
        if (grp >= ngroups) break;                 // uniform across block
        int sp = (grp * 4 + wv) * 16 + m16;
        const bool active = sp < BS;
        int spc = active ? sp : 0;

        // ---- st loads (5 floats; 4 lane-groups read same addresses -> cached) ----
        float st0 = buf[0*(size_t)BS + spc];
        float st1 = buf[1*(size_t)BS + spc];
        float st2 = buf[2*(size_t)BS + spc];
        float st3 = buf[3*(size_t)BS + spc];
        float st4 = buf[4*(size_t)BS + spc];

        // ---- h1 at i = 16*it + 4*g4 + r (16 tanh per lane) ----
        f32x4 h1v[4];
        #pragma unroll
        for (int it = 0; it < 4; ++it) {
            const int off = it*16 + g4*4;
            f32x4 b1f = *(const f32x4*)&sPar[320 + off];
            f32x4 wa = *(const f32x4*)&sPar[0*64 + off];
            f32x4 wb = *(const f32x4*)&sPar[1*64 + off];
            f32x4 wc = *(const f32x4*)&sPar[2*64 + off];
            f32x4 wd = *(const f32x4*)&sPar[3*64 + off];
            f32x4 we = *(const f32x4*)&sPar[4*64 + off];
            #pragma unroll
            for (int r = 0; r < 4; ++r) {
                float z1 = b1f[r] + st0*wa[r] + st1*wb[r] + st2*wc[r]
                         + st3*wd[r] + st4*we[r];
                h1v[it][r] = tanh_fast(z1);
            }
        }

        // ---- pack h1 into B fragments (slot order = lambda) ----
        short8 bh0, bl0, bh1, bl1;
        pack8v(h1v[0], h1v[1], bh0, bl0);   // kc=0: it 0,1
        pack8v(h1v[2], h1v[3], bh1, bl1);   // kc=1: it 2,3

        // ---- forward: z2^T[o][spring], acc[ot] covers o = ot*16 + 4*g4 + r ----
        f32x4 acc[4];
        #pragma unroll
        for (int ot = 0; ot < 4; ++ot) acc[ot] = b2v[ot];

        #pragma unroll
        for (int ot = 0; ot < 4; ++ot) {
            short8 ah0 = Afh[(ot*2+0)*64 + lane];
            short8 al0 = Afl[(ot*2+0)*64 + lane];
            short8 ah1 = Afh[(ot*2+1)*64 + lane];
            short8 al1 = Afl[(ot*2+1)*64 + lane];
            acc[ot] = MFMA_BF16(ah0, bh0, acc[ot], 0, 0, 0);
            acc[ot] = MFMA_BF16(ah0, bl0, acc[ot], 0, 0, 0);
            acc[ot] = MFMA_BF16(al0, bh0, acc[ot], 0, 0, 0);
            acc[ot] = MFMA_BF16(ah1, bh1, acc[ot], 0, 0, 0);
            acc[ot] = MFMA_BF16(ah1, bl1, acc[ot], 0, 0, 0);
            acc[ot] = MFMA_BF16(al1, bh1, acc[ot], 0, 0, 0);
        }

        // ---- middle: h2 = tanh(z2); z3 = h2.W3 (+2 shfl); sig; gz2 in place ----
        float z3 = 0.f;
        #pragma unroll
        for (int ot = 0; ot < 4; ++ot)
            #pragma unroll
            for (int r = 0; r < 4; ++r) {
                float h2 = tanh_fast(acc[ot][r]);
                acc[ot][r] = h2;
                z3 = fmaf(h2, w3v[ot][r], z3);
            }
        z3 += __shfl_xor(z3, 16, 64);
        z3 += __shfl_xor(z3, 32, 64);
        z3 += b3v;
        float sig = rcpf(1.f + __expf(-z3));       // softplus'

        #pragma unroll
        for (int ot = 0; ot < 4; ++ot)
            #pragma unroll
            for (int r = 0; r < 4; ++r) {
                float h2 = acc[ot][r];
                acc[ot][r] = sig * w3v[ot][r] * (1.f - h2*h2);
            }

        // ---- backward: g[i][spring] = W2 @ gz2 ; B feeds directly from acc ----
        pack8v(acc[0], acc[1], bh0, bl0);   // kc=0: o-tiles 0,1
        pack8v(acc[2], acc[3], bh1, bl1);   // kc=1: o-tiles 2,3

        f32x4 gg[4];
        #pragma unroll
        for (int it = 0; it < 4; ++it) gg[it] = (f32x4){0.f, 0.f, 0.f, 0.f};

        #pragma unroll
        for (int it = 0; it < 4; ++it) {
            short8 ah0 = Abh[(it*2+0)*64 + lane];
            short8 al0 = Abl[(it*2+0)*64 + lane];
            short8 ah1 = Abh[(it*2+1)*64 + lane];
            short8 al1 = Abl[(it*2+1)*64 + lane];
            gg[it] = MFMA_BF16(ah0, bh0, gg[it], 0, 0, 0);
            gg[it] = MFMA_BF16(ah0, bl0, gg[it], 0, 0, 0);
            gg[it] = MFMA_BF16(al0, bh0, gg[it], 0, 0, 0);
            gg[it] = MFMA_BF16(ah1, bh1, gg[it], 0, 0, 0);
            gg[it] = MFMA_BF16(ah1, bl1, gg[it], 0, 0, 0);
            gg[it] = MFMA_BF16(al1, bh1, gg[it], 0, 0, 0);
        }

        // ---- gz1 = g*(1-h1^2); gs partials; reduce over lane-groups ----
        float p0 = 0.f, p1 = 0.f, p2 = 0.f, p3 = 0.f, p4 = 0.f;
        #pragma unroll
        for (int it = 0; it < 4; ++it) {
            const int off = it*16 + g4*4;
            f32x4 wa = *(const f32x4*)&sPar[0*64 + off];
            f32x4 wb = *(const f32x4*)&sPar[1*64 + off];
            f32x4 wc = *(const f32x4*)&sPar[2*64 + off];
            f32x4 wd = *(const f32x4*)&sPar[3*64 + off];
            f32x4 we = *(const f32x4*)&sPar[4*64 + off];
            #pragma unroll
            for (int r = 0; r < 4; ++r) {
                float hv = h1v[it][r];
                float gz1 = gg[it][r] * (1.f - hv*hv);
                p0 = fmaf(gz1, wa[r], p0);
                p1 = fmaf(gz1, wb[r], p1);
                p2 = fmaf(gz1, wc[r], p2);
                p3 = fmaf(gz1, wd[r], p3);
                p4 = fmaf(gz1, we[r], p4);
            }
        }
        p0 += __shfl_xor(p0, 16, 64); p0 += __shfl_xor(p0, 32, 64);
        p1 += __shfl_xor(p1, 16, 64); p1 += __shfl_xor(p1, 32, 64);
        p2 += __shfl_xor(p2, 16, 64); p2 += __shfl_xor(p2, 32, 64);
        p3 += __shfl_xor(p3, 16, 64); p3 += __shfl_xor(p3, 32, 64);
        p4 += __shfl_xor(p4, 16, 64); p4 += __shfl_xor(p4, 32, 64);

        // ---- write gs in place over st (own spring; reads above complete) ----
        if (active && g4 == 0) {
            buf[0*(size_t)BS + sp] = p0;
            buf[1*(size_t)BS + sp] = p1;
            buf[2*(size_t)BS + sp] = p2;
            buf[3*(size_t)BS + sp] = p3;
            buf[4*(size_t)BS + sp] = p4;
        }
    }
}

// ---------------- stage 3: geometry backward (per-thread, full lane util) ----------------
__global__ __launch_bounds__(256) void k_geom_bwd(
    const float* __restrict__ x,
    float* buf,                         // gs in / fs out, [11][BS]
    const float* __restrict__ l0e,
    const float* __restrict__ d1i, const float* __restrict__ d2i,
    const int* __restrict__ springs,
    int B, int S, int ndof, int nodal)
{
    int sp = blockIdx.x * 256 + threadIdx.x;
    int BS = B * S;
    if (sp >= BS) return;
    int b = sp / S;
    int s = sp - b * S;
    const int* spr = springs + 5 * s;
    const float* q = x + (size_t)b * (size_t)(2 * ndof);
    Geom G = compute_geom(q, spr, l0e, d1i, d2i, nodal);
    float gs0 = buf[0*(size_t)BS + sp];
    float gs1 = buf[1*(size_t)BS + sp];
    float gs2 = buf[2*(size_t)BS + sp];
    float gs3 = buf[3*(size_t)BS + sp];
    float gs4 = buf[4*(size_t)BS + sp];
    geom_backward_store(G, gs0, gs1, gs2, gs3, gs4, buf + sp, (size_t)BS);
}

// ---------------- fallback: scalar per-thread kernel with atomics ----------------
__global__ __launch_bounds__(256) void k_force_scalar(
    const float* __restrict__ x,
    const float* __restrict__ W1, const float* __restrict__ b1,
    const float* __restrict__ W2, const float* __restrict__ b2,
    const float* __restrict__ W3, const float* __restrict__ b3,
    const float* __restrict__ Mff,
    const float* __restrict__ l0e,
    const float* __restrict__ d1i, const float* __restrict__ d2i,
    const int* __restrict__ springs,
    float* __restrict__ out,
    int B, int S, int ndof, int nodal)
{
    int tid = blockIdx.x * 256 + threadIdx.x;
    if (tid >= B * S) return;
    int b = tid / S;
    int s = tid - b * S;
    const int* spr = springs + 5 * s;
    const float* q = x + (size_t)b * (size_t)(2 * ndof);
    Geom G = compute_geom(q, spr, l0e, d1i, d2i, nodal);
    float st0 = G.st0, st1 = G.st1, st2 = G.st2, st3 = G.st3, st4 = G.st4;

    const float4* W2v = reinterpret_cast<const float4*>(W2);
    float accv[64];
    #pragma unroll
    for (int j = 0; j < 64; ++j) accv[j] = b2[j];
    #pragma unroll 4
    for (int i = 0; i < 64; ++i) {
        float z1 = b1[i] + st0*W1[i] + st1*W1[64+i] + st2*W1[128+i]
                 + st3*W1[192+i] + st4*W1[256+i];
        float hi = tanh_fast(z1);
        #pragma unroll
        for (int j4 = 0; j4 < 16; ++j4) {
            float4 w = W2v[i*16 + j4];
            accv[4*j4+0] = fmaf(hi, w.x, accv[4*j4+0]);
            accv[4*j4+1] = fmaf(hi, w.y, accv[4*j4+1]);
            accv[4*j4+2] = fmaf(hi, w.z, accv[4*j4+2]);
            accv[4*j4+3] = fmaf(hi, w.w, accv[4*j4+3]);
        }
    }
    float z3 = b3[0];
    #pragma unroll
    for (int j = 0; j < 64; ++j) {
        float h2 = tanh_fast(accv[j]); accv[j] = h2;
        z3 = fmaf(h2, W3[j], z3);
    }
    float sig = rcpf(1.f + __expf(-z3));
    #pragma unroll
    for (int j = 0; j < 64; ++j) {
        float h2 = accv[j];
        accv[j] = sig * W3[j] * (1.f - h2*h2);
    }
    float gs0 = 0.f, gs1 = 0.f, gs2 = 0.f, gs3 = 0.f, gs4 = 0.f;
    #pragma unroll 4
    for (int i = 0; i < 64; ++i) {
        float g0 = 0.f;
        #pragma unroll
        for (int j4 = 0; j4 < 16; ++j4) {
            float4 w = W2v[i*16 + j4];
            g0 += w.x*accv[4*j4+0] + w.y*accv[4*j4+1] + w.z*accv[4*j4+2] + w.w*accv[4*j4+3];
        }
        float z1 = b1[i] + st0*W1[i] + st1*W1[64+i] + st2*W1[128+i]
                 + st3*W1[192+i] + st4*W1[256+i];
        float h1 = tanh_fast(z1);
        float gz1 = g0 * (1.f - h1*h1);
        gs0 = fmaf(W1[i],     gz1, gs0);
        gs1 = fmaf(W1[64+i],  gz1, gs1);
        gs2 = fmaf(W1[128+i], gz1, gs2);
        gs3 = fmaf(W1[192+i], gz1, gs3);
        gs4 = fmaf(W1[256+i], gz1, gs4);
    }
    float gkb0 = 0.5f*(gs2*G.m2s0 - gs3*G.m1s0);
    float gkb1 = 0.5f*(gs2*G.m2s1 - gs3*G.m1s1);
    float gkb2 = 0.5f*(gs2*G.m2s2 - gs3*G.m1s2);
    float kbm1p = G.kb0*G.m1p0 + G.kb1*G.m1p1 + G.kb2*G.m1p2;
    float kbm2p = G.kb0*G.m2p0 + G.kb1*G.m2p1 + G.kb2*G.m2p2;
    float kbm1n = G.kb0*G.m1n0 + G.kb1*G.m1n1 + G.kb2*G.m1n2;
    float kbm2n = G.kb0*G.m2n0 + G.kb1*G.m2n1 + G.kb2*G.m2n2;
    float gthp = -gs4 - 0.5f*(gs2*kbm1p + gs3*kbm2p);
    float gthn =  gs4 - 0.5f*(gs2*kbm1n + gs3*kbm2n);
    float gcr0 = 2.f*gkb0*G.idenom, gcr1 = 2.f*gkb1*G.idenom, gcr2 = 2.f*gkb2*G.idenom;
    float gc = -(gkb0*G.kb0 + gkb1*G.kb1 + gkb2*G.kb2)*G.idenom;
    float gtp0 = G.tn1*gcr2 - G.tn2*gcr1 + gc*G.tn0;
    float gtp1 = G.tn2*gcr0 - G.tn0*gcr2 + gc*G.tn1;
    float gtp2 = G.tn0*gcr1 - G.tn1*gcr0 + gc*G.tn2;
    float gtn0 = gcr1*G.tp2 - gcr2*G.tp1 + gc*G.tp0;
    float gtn1 = gcr2*G.tp0 - gcr0*G.tp2 + gc*G.tp1;
    float gtn2 = gcr0*G.tp1 - gcr1*G.tp0 + gc*G.tp2;
    float gep0 = gtp0*G.ilp, gep1 = gtp1*G.ilp, gep2 = gtp2*G.ilp;
    float gilp = gtp0*G.ep0 + gtp1*G.ep1 + gtp2*G.ep2;
    float glp  = gs0*G.il0p - gilp*G.ilp*G.ilp;
    float tl   = glp*rcpf(G.lp);
    gep0 = fmaf(tl, G.ep0, gep0); gep1 = fmaf(tl, G.ep1, gep1); gep2 = fmaf(tl, G.ep2, gep2);
    float gen0 = gtn0*G.iln, gen1 = gtn1*G.iln, gen2 = gtn2*G.iln;
    float giln = gtn0*G.en0 + gtn1*G.en1 + gtn2*G.en2;
    float gln  = gs1*G.il0n - giln*G.iln*G.iln;
    float ul   = gln*rcpf(G.ln);
    gen0 = fmaf(ul, G.en0, gen0); gen1 = fmaf(ul, G.en1, gen1); gen2 = fmaf(ul, G.en2, gen2);
    float* oa = out + (size_t)b * (size_t)(2*ndof) + ndof;
    const size_t nd1 = (size_t)ndof + 1;
    int ni = spr[0], nj = spr[1], nk = spr[2];
    int di = 3*ni, dj = 3*nj, dk = 3*nk, dp = nodal + spr[3], dn = nodal + spr[4];
    atomicAdd(oa + di + 0, ( gep0) * rcpf(Mff[(size_t)(di+0)*nd1]));
    atomicAdd(oa + di + 1, ( gep1) * rcpf(Mff[(size_t)(di+1)*nd1]));
    atomicAdd(oa + di + 2, ( gep2) * rcpf(Mff[(size_t)(di+2)*nd1]));
    atomicAdd(oa + dj + 0, (gen0-gep0) * rcpf(Mff[(size_t)(dj+0)*nd1]));
    atomicAdd(oa + dj + 1, (gen1-gep1) * rcpf(Mff[(size_t)(dj+1)*nd1]));
    atomicAdd(oa + dj + 2, (gen2-gep2) * rcpf(Mff[(size_t)(dj+2)*nd1]));
    atomicAdd(oa + dk + 0, (-gen0) * rcpf(Mff[(size_t)(dk+0)*nd1]));
    atomicAdd(oa + dk + 1, (-gen1) * rcpf(Mff[(size_t)(dk+1)*nd1]));
    atomicAdd(oa + dk + 2, (-gen2) * rcpf(Mff[(size_t)(dk+2)*nd1]));
    atomicAdd(oa + dp, (-gthp) * rcpf(Mff[(size_t)dp*nd1]));
    atomicAdd(oa + dn, (-gthn) * rcpf(Mff[(size_t)dn*nd1]));
}

// out[:, :ndof] = v ; out[:, ndof:] = (f_ext - Cdd*v + gather(fs)) / Mdd
// fs layout: [11][BS] spring-major (slot stride BS, spring index b*S+s)
template<int GATHER>
__global__ void k_out(const float* __restrict__ x, const float* __restrict__ C,
                      const float* __restrict__ Mff, const float* __restrict__ fext,
                      const float* __restrict__ fs, float* __restrict__ out,
                      int B, int ndof, int nodal, int S) {
    int idx = blockIdx.x * blockDim.x + threadIdx.x;
    if (idx >= B * ndof) return;
    int b = idx / ndof;
    int d = idx - b * ndof;
    size_t row = (size_t)b * (size_t)(2 * ndof);
    const size_t nd1 = (size_t)ndof + 1;
    float vd = x[row + ndof + d];
    out[row + d] = vd;
    float acc = fext[d] - C[(size_t)d * nd1] * vd;
    if (GATHER) {
        const size_t BS = (size_t)B * S;
        const size_t bb = (size_t)b * S;
        if (d < nodal) {
            int n = d / 3, c = d - 3 * n;
            if (n < S)            acc += fs[(size_t)(0 + c) * BS + bb + n];
            if (n >= 1 && n <= S) acc += fs[(size_t)(3 + c) * BS + bb + n - 1];
            if (n >= 2)           acc += fs[(size_t)(6 + c) * BS + bb + n - 2];
        } else {
            int e = d - nodal;
            if (e < S)  acc += fs[(size_t)9 * BS + bb + e];
            if (e >= 1) acc += fs[(size_t)10 * BS + bb + e - 1];
        }
    }
    out[row + ndof + d] = acc * rcpf(Mff[(size_t)d * nd1]);
}

extern "C" void kernel_launch(void* const* d_in, const int* in_sizes, int n_in,
                              void* d_out, int out_size, void* d_ws, size_t ws_size,
                              hipStream_t stream) {
    const float* x    = (const float*)d_in[1];
    const float* W1   = (const float*)d_in[2];
    const float* b1   = (const float*)d_in[3];
    const float* W2   = (const float*)d_in[4];
    const float* b2   = (const float*)d_in[5];
    const float* W3   = (const float*)d_in[6];
    const float* b3   = (const float*)d_in[7];
    const float* C    = (const float*)d_in[8];
    const float* Mff  = (const float*)d_in[9];
    const float* fext = (const float*)d_in[10];
    const float* l0e  = (const float*)d_in[11];
    const float* d1i  = (const float*)d_in[12];
    const float* d2i  = (const float*)d_in[13];
    const int* springs = (const int*)d_in[14];
    float* out = (float*)d_out;

    int ndof  = in_sizes[10];
    int E     = in_sizes[11];
    int S     = in_sizes[14] / 5;
    int nodal = ndof - E;
    int B     = in_sizes[1] / (2 * ndof);

    int BS   = B * S;
    int totO = B * ndof;
    const size_t fragBytes = 34848;   // 32768 frag + 2080 params (16-aligned)
    size_t ws_need = fragBytes + (size_t)BS * 11 * sizeof(float);

    if (d_ws && ws_size >= ws_need) {
        short* wfrag = (short*)d_ws;
        float* buf = (float*)((char*)d_ws + fragBytes);   // st -> gs -> fs (overlaid)
        k_prep<<<1, 256, 0, stream>>>(W2, W1, b1, b2, W3, b3, wfrag);
        int nblkT = (BS + 255) / 256;
        k_strain<<<nblkT, 256, 0, stream>>>(x, l0e, d1i, d2i, springs, buf,
                                            B, S, ndof, nodal);
        int ngroups = (BS + 63) / 64;                 // 64-spring groups
        int nblkM = (ngroups + CHUNK - 1) / CHUNK;    // CHUNK groups per block
        k_mlp<<<nblkM, 256, 0, stream>>>(wfrag, buf, BS, ngroups);
        k_geom_bwd<<<nblkT, 256, 0, stream>>>(x, buf, l0e, d1i, d2i, springs,
                                              B, S, ndof, nodal);
        k_out<1><<<(totO + 255) / 256, 256, 0, stream>>>(x, C, Mff, fext, buf, out,
                                                         B, ndof, nodal, S);
    } else {
        k_out<0><<<(totO + 255) / 256, 256, 0, stream>>>(x, C, Mff, fext, nullptr, out,
                                                         B, ndof, nodal, S);
        k_force_scalar<<<(BS + 255) / 256, 256, 0, stream>>>(x, W1, b1, W2, b2, W3, b3, Mff,
                                                             l0e, d1i, d2i, springs, out,
                                                             B, S, ndof, nodal);
    }
}